// Round 19
// baseline (124.309 us; speedup 1.0000x reference)
//
#include <hip/hip_runtime.h>

#define DM 1024
#define HN 16
#define HD 64
#define BB 8
#define LL 512

typedef __bf16 bf16x8 __attribute__((ext_vector_type(8)));
typedef __bf16 bf16x4 __attribute__((ext_vector_type(4)));
typedef float  f32x4  __attribute__((ext_vector_type(4)));

__device__ __forceinline__ void cvt8(const float* __restrict__ in,
                                     __bf16* __restrict__ out, int i) {
    const float4* p = (const float4*)in + (size_t)i * 2;
    float4 a = p[0], b = p[1];
    bf16x8 v;
    v[0] = (__bf16)a.x; v[1] = (__bf16)a.y; v[2] = (__bf16)a.z; v[3] = (__bf16)a.w;
    v[4] = (__bf16)b.x; v[5] = (__bf16)b.y; v[6] = (__bf16)b.z; v[7] = (__bf16)b.w;
    ((bf16x8*)out)[i] = v;
}

// ---------------- fused prep: sortq + schedule + PE + all f32->bf16 cvts -------
__global__ __launch_bounds__(512) void prep_kernel(
    const int* __restrict__ qmask, const int* __restrict__ maskp,
    const float* __restrict__ x, const float* __restrict__ W_qkv,
    const float* __restrict__ W_pos, const float* __restrict__ W_fc,
    int* __restrict__ perm, int* __restrict__ pmask, float* __restrict__ posf,
    int* __restrict__ nzA, int* __restrict__ sched,
    __bf16* __restrict__ PEb, __bf16* __restrict__ Wposb,
    __bf16* __restrict__ Wfcb, __bf16* __restrict__ Xb, __bf16* __restrict__ Wqkvb)
{
    const int blk = blockIdx.x, tid = threadIdx.x;
    if (blk < 8) {                       // ---- sortq + schedule ----
        int b = blk, i = tid;
        int qm = qmask[b * LL + i];
        unsigned long long bz = __ballot(qm == 0);
        int wid = i >> 6, lane = i & 63;
        __shared__ int wz[8];
        int pzw = __popcll(bz & ((1ULL << lane) - 1ULL));
        if (lane == 0) wz[wid] = __popcll(bz);
        __syncthreads();
        int base = 0, nz = 0;
#pragma unroll
        for (int w2 = 0; w2 < 8; ++w2) { int c = wz[w2]; if (w2 < wid) base += c; nz += c; }
        int zbefore = base + pzw;
        int pos = (qm == 0) ? zbefore : (nz + (i - zbefore));
        perm[b * LL + pos] = i;
        pmask[b * LL + pos] = maskp[b * LL + i];
        posf[b * LL + pos] = (float)i;
        if (i == 0) nzA[b] = nz;
        if (i < 16) {                    // mixed qt first per XCD group
            int bh2 = b * 16 + i;
            int g = i & 7;
            int idx = b * 2 + (i >> 3);
            int qtm = nz >> 7; if (qtm > 3) qtm = 3;
            sched[idx * 8 + g] = (bh2 << 2) | qtm;
#pragma unroll
            for (int j = 0; j < 3; ++j) {
                int qtj = j + (j >= qtm ? 1 : 0);
                sched[(16 + idx * 3 + j) * 8 + g] = (bh2 << 2) | qtj;
            }
        }
    } else if (blk < 72) {               // ---- PE table [512][64] bf16 ----
        int idx = (blk - 8) * 512 + tid;
        int l = idx >> 6, d = idx & 63;
        float p = (float)(l - LL / 2);
        const float cexp = -9.210340371976184f / 31.0f;
        float val;
        if (d < 32) { float f = expf((float)d * cexp);        val = sinf(p * f); }
        else        { float f = expf((float)(d - 32) * cexp); val = cosf(p * f); }
        PEb[idx] = (__bf16)val;
    } else if (blk < 120) {
        cvt8(W_pos, Wposb, (blk - 72) * 512 + tid);
    } else if (blk < 376) {
        cvt8(W_fc, Wfcb, (blk - 120) * 512 + tid);
    } else if (blk < 1400) {
        cvt8(x, Xb, (blk - 376) * 512 + tid);
    } else if (blk < 1656) {
        cvt8(W_qkv, Wqkvb, (blk - 1400) * 512 + tid);
    } else {
        cvt8(W_qkv + 2097152, Wqkvb + 1048576, (blk - 1656) * 512 + tid);
    }
}

// ------- fused QKV + pos-proj GEMM (r17-proven) ----
__global__ __launch_bounds__(256, 4) void gemm_fused(
    const __bf16* __restrict__ Xb, const __bf16* __restrict__ Wqkvb,
    const __bf16* __restrict__ PEb, const __bf16* __restrict__ Wposb,
    __bf16* __restrict__ Qc, __bf16* __restrict__ K1c,
    __bf16* __restrict__ K2c, __bf16* __restrict__ Vn)
{
    __shared__ __bf16 smem[128 * 136];
    __bf16* As = smem;
    __bf16* Bs = smem + 8192;
    __bf16* Cs = smem;
    const int tid = threadIdx.x;
    const int lane = tid & 63;
    const int w = tid >> 6;
    const int wm = w >> 1, wn = w & 1;

    const bool isPos = (blockIdx.x >= 1024);
    const int bi = isPos ? (blockIdx.x - 1024) : blockIdx.x;
    const int n0 = isPos ? (bi % 24) * 128 : (bi & 31) * 128;
    const int m0 = isPos ? (bi / 24) * 128 : (bi >> 5) * 128;
    const int K  = isPos ? 64 : 1024;
    const __bf16* A  = isPos ? PEb : Xb;
    const __bf16* Bm = isPos ? Wposb : Wqkvb;

    const int fr = lane & 15;
    const int fq = lane >> 4;

    const int srow = tid >> 3;
    const int scol = (tid & 7) ^ (srow & 7);
    const __bf16* Ag = A + (size_t)(m0 + srow) * K + scol * 8;
    const __bf16* Bg = Bm + (size_t)(n0 + srow) * K + scol * 8;
    char* AsB = (char*)As + (size_t)w * 1024;
    char* BsB = (char*)Bs + (size_t)w * 1024;

    f32x4 acc[4][4] = {};

    for (int k0 = 0; k0 < K; k0 += 64) {
#pragma unroll
        for (int r = 0; r < 4; ++r) {
            __builtin_amdgcn_global_load_lds(Ag + k0 + (size_t)(r * 32) * K, AsB + r * 4096, 16, 0, 0);
            __builtin_amdgcn_global_load_lds(Bg + k0 + (size_t)(r * 32) * K, BsB + r * 4096, 16, 0, 0);
        }
        __syncthreads();

#pragma unroll
        for (int kk = 0; kk < 2; ++kk) {
            const int so = ((kk * 4 + fq) ^ (fr & 7)) * 8;
            bf16x8 af[4], bfr[4];
#pragma unroll
            for (int i = 0; i < 4; ++i)
                af[i] = *(const bf16x8*)(As + (size_t)(wm * 64 + i * 16 + fr) * 64 + so);
#pragma unroll
            for (int j = 0; j < 4; ++j)
                bfr[j] = *(const bf16x8*)(Bs + (size_t)(wn * 64 + j * 16 + fr) * 64 + so);
#pragma unroll
            for (int i = 0; i < 4; ++i)
#pragma unroll
                for (int j = 0; j < 4; ++j)
                    acc[i][j] = __builtin_amdgcn_mfma_f32_16x16x32_bf16(bfr[j], af[i], acc[i][j], 0, 0, 0);
        }
        __syncthreads();
    }

#pragma unroll
    for (int i = 0; i < 4; ++i) {
        int mloc = wm * 64 + i * 16 + fr;
#pragma unroll
        for (int j = 0; j < 4; ++j) {
            int nloc = wn * 64 + j * 16 + fq * 4;
            bf16x4 v;
#pragma unroll
            for (int r = 0; r < 4; ++r) v[r] = (__bf16)acc[i][j][r];
            *(bf16x4*)(Cs + (size_t)mloc * 136 + nloc) = v;
        }
    }
    __syncthreads();
    if (!isPos) {
        const int c = n0 >> 10;
        __bf16* T = (c == 0) ? Qc : (c == 1) ? K1c : (c == 2) ? K2c : Vn;
        const int b = m0 >> 9, l0 = m0 & 511, h0 = (n0 >> 6) & 15;
#pragma unroll
        for (int rnd = 0; rnd < 8; ++rnd) {
            int Ci = rnd * 256 + tid;
            int m = Ci >> 4, nch = Ci & 15;
            bf16x8 v = *(const bf16x8*)(Cs + (size_t)m * 136 + nch * 8);
            int hl = nch >> 3, d = (nch & 7) * 8;
            size_t bh2 = (size_t)(b * HN + h0 + hl);
            if (c < 3) *(bf16x8*)(T + (bh2 * LL + l0 + m) * 128 + d) = v;
            else       *(bf16x8*)(T + (bh2 * LL + l0 + m) * 64  + d) = v;
        }
    } else {
        const int c = n0 >> 10;
        __bf16* T = (c == 0) ? Qc : (c == 1) ? K1c : K2c;
#pragma unroll
        for (int rnd = 0; rnd < 8; ++rnd) {
            int Ci = rnd * 256 + tid;
            int m = Ci >> 4, nch = Ci & 15;
            bf16x8 v = *(const bf16x8*)(Cs + (size_t)m * 136 + nch * 8);
            int eg = n0 + nch * 8;
            int h = (eg >> 6) & 15, d = eg & 63;
            size_t off = ((size_t)h * LL + (m0 + m)) * 128 + 64 + d;
#pragma unroll
            for (int b = 0; b < 8; ++b)
                *(bf16x8*)(T + (size_t)b * (HN * LL * 128) + off) = v;
        }
    }
}

// ---------------- out-proj GEMM ----------------
__global__ __launch_bounds__(256, 4) void gemm_out(
    const __bf16* __restrict__ A, const __bf16* __restrict__ Bm,
    float* __restrict__ outF, const float* __restrict__ bias)
{
    __shared__ __bf16 smem[128 * 136];
    __bf16* As = smem;
    __bf16* Bs = smem + 8192;
    const int tid = threadIdx.x;
    const int lane = tid & 63;
    const int w = tid >> 6;
    const int wm = w >> 1, wn = w & 1;
    const int n0 = blockIdx.x * 128;
    const int m0 = blockIdx.y * 128;
    const int fr = lane & 15;
    const int fq = lane >> 4;
    const int K = 1024;

    const int srow = tid >> 3;
    const int scol = (tid & 7) ^ (srow & 7);
    const __bf16* Ag = A + (size_t)(m0 + srow) * K + scol * 8;
    const __bf16* Bg = Bm + (size_t)(n0 + srow) * K + scol * 8;
    char* AsB = (char*)As + (size_t)w * 1024;
    char* BsB = (char*)Bs + (size_t)w * 1024;

    f32x4 acc[4][4] = {};

    for (int k0 = 0; k0 < K; k0 += 64) {
#pragma unroll
        for (int r = 0; r < 4; ++r) {
            __builtin_amdgcn_global_load_lds(Ag + k0 + (size_t)(r * 32) * K, AsB + r * 4096, 16, 0, 0);
            __builtin_amdgcn_global_load_lds(Bg + k0 + (size_t)(r * 32) * K, BsB + r * 4096, 16, 0, 0);
        }
        __syncthreads();

#pragma unroll
        for (int kk = 0; kk < 2; ++kk) {
            const int so = ((kk * 4 + fq) ^ (fr & 7)) * 8;
            bf16x8 af[4], bfr[4];
#pragma unroll
            for (int i = 0; i < 4; ++i)
                af[i] = *(const bf16x8*)(As + (size_t)(wm * 64 + i * 16 + fr) * 64 + so);
#pragma unroll
            for (int j = 0; j < 4; ++j)
                bfr[j] = *(const bf16x8*)(Bs + (size_t)(wn * 64 + j * 16 + fr) * 64 + so);
#pragma unroll
            for (int i = 0; i < 4; ++i)
#pragma unroll
                for (int j = 0; j < 4; ++j)
                    acc[i][j] = __builtin_amdgcn_mfma_f32_16x16x32_bf16(bfr[j], af[i], acc[i][j], 0, 0, 0);
        }
        __syncthreads();
    }

#pragma unroll
    for (int i = 0; i < 4; ++i) {
        int m = m0 + wm * 64 + i * 16 + fr;
#pragma unroll
        for (int j = 0; j < 4; ++j) {
            int nn = n0 + wn * 64 + j * 16 + fq * 4;
            float4 bv = *(const float4*)(bias + nn);
            *(float4*)(outF + (size_t)m * DM + nn) =
                make_float4(acc[i][j][0] + bv.x, acc[i][j][1] + bv.y,
                            acc[i][j][2] + bv.z, acc[i][j][3] + bv.w);
        }
    }
}

// -------- V transpose + key permute -------
__global__ __launch_bounds__(256) void vtrans_kernel(const __bf16* __restrict__ Vn,
                                                     const int* __restrict__ perm,
                                                     __bf16* __restrict__ Vt) {
    __shared__ __bf16 Ts[64][72];
    int bh = blockIdx.x >> 3, lt = blockIdx.x & 7;
    int b = bh >> 4;
    int r = threadIdx.x >> 2, s = threadIdx.x & 3;
    int orow = perm[b * LL + lt * 64 + r];
    const __bf16* src = Vn + ((size_t)bh * LL + orow) * 64;
    *(bf16x8*)&Ts[r][s * 16]     = *(const bf16x8*)(src + s * 16);
    *(bf16x8*)&Ts[r][s * 16 + 8] = *(const bf16x8*)(src + s * 16 + 8);
    __syncthreads();
    __bf16* dst = Vt + ((size_t)bh * 64 + r) * LL + lt * 64 + s * 16;
    bf16x8 a, bvv;
#pragma unroll
    for (int e = 0; e < 8; ++e) { a[e] = Ts[s * 16 + e][r]; bvv[e] = Ts[s * 16 + 8 + e][r]; }
    *(bf16x8*)dst = a;
    *(bf16x8*)(dst + 8) = bvv;
}

// ------- MFMA flash attention (r18 + lane-partial lrun + posf-direct loads) ------
// Per-tile cross-lane SUM shuffles removed: lrun kept lane-partial (rescale sc is
// row-uniform), one final 2-shuffle reduce. posL staging dropped: gaussian reads
// posf directly (broadcast f32x4, L1/L2-served).
__global__ __launch_bounds__(512, 2) void attn_kernel(
    const __bf16* __restrict__ Qc, const __bf16* __restrict__ K1c,
    const __bf16* __restrict__ K2c, const __bf16* __restrict__ Vt,
    const int* __restrict__ pmask, const int* __restrict__ perm,
    const float* __restrict__ posf, const int* __restrict__ nzA,
    const int* __restrict__ sched,
    const float* __restrict__ shiftp, __bf16* __restrict__ AO)
{
    __shared__ __bf16 Ke0[64 * 136];
    __shared__ __bf16 Ke1[64 * 136];
    __shared__ __bf16 Vts[2][64 * 72];
    __shared__ __bf16 Sb[8 * 16 * 40];

    const int tid = threadIdx.x;
    const int lane = tid & 63;
    const int wid = tid >> 6;
    const int fr = lane & 15;
    const int fq = lane >> 4;

    const int e = sched[blockIdx.x];
    const int qt = e & 3;
    const int h  = (e >> 2) & 15;
    const int b  = e >> 6;
    const size_t bh = (size_t)(b * HN + h);
    const int nz = nzA[b];
    const int q0blk = qt * 128;
    const int s = q0blk + wid * 16 + fr;
    const int pi = perm[b * LL + s];
    const bool need0 = (q0blk < nz);
    const bool need1 = (q0blk + 127 >= nz);
    const int w0 = q0blk + wid * 16;
    const bool wneed0 = (w0 < nz);
    const bool wneed1 = (w0 + 15 >= nz);
    const int qmI = (s >= nz) ? 1 : 0;

    const float sft = shiftp[0];

    bf16x8 qf[4];
    {
        const __bf16* qrow = Qc + (bh * LL + pi) * 128;
#pragma unroll
        for (int kf = 0; kf < 4; ++kf)
            qf[kf] = *(const bf16x8*)(qrow + kf * 32 + fq * 8);
    }

    float mrun = -1e30f, lrun = 0.f;
    f32x4 ot[4] = {};
    const float qposf = (float)pi;

    const __bf16* K1g0 = K1c + bh * LL * 128;
    const __bf16* K2g0 = K2c + bh * LL * 128;
    const __bf16* Vtg0 = Vt + bh * 64 * LL;
    const float* posg = posf + b * LL;
    __bf16* Sw = Sb + wid * 16 * 40;

    const int krr = tid >> 4;      // 0..31
    const int ku  = tid & 15;
    const int vrr = tid >> 3;      // 0..63
    const int vu  = tid & 7;

    if (!(need0 && need1)) {
        // ===== PURE: 8 tiles x 64 keys, double-buffered, ONE barrier/tile =====
        const __bf16* KA = need0 ? K1g0 : K2g0;
        const __bf16* KB = need0 ? K2g0 : K1g0;
        bf16x8 rk[2], rv;
        int pm;

#define LOADP(tt)                                                                  \
    {                                                                              \
        int j0_ = (tt) * 64;                                                       \
        _Pragma("unroll")                                                          \
        for (int p = 0; p < 2; ++p) {                                              \
            int sr = j0_ + p * 32 + krr;                                           \
            int orow = perm[b * LL + sr];                                          \
            rk[p] = *(const bf16x8*)(((sr >= nz) ? KB : KA) + (size_t)orow * 128 + ku * 8); \
        }                                                                          \
        rv = *(const bf16x8*)(Vtg0 + (size_t)vrr * LL + j0_ + vu * 8);             \
        pm = pmask[b * LL + j0_ + lane];                                           \
    }

#define STAGEP(buf)                                                                \
    {                                                                              \
        __bf16* Kd = (buf) ? Ke1 : Ke0;                                            \
        _Pragma("unroll")                                                          \
        for (int p = 0; p < 2; ++p) {                                              \
            int rr = p * 32 + krr;                                                 \
            *(bf16x8*)(Kd + rr * 136 + ku * 8) = rk[p];                            \
        }                                                                          \
        *(bf16x8*)(Vts[buf] + vrr * 72 + vu * 8) = rv;                             \
    }

        LOADP(0);
        STAGEP(0);
        unsigned long long kb_next = __ballot(pm != 0);
        LOADP(1);
        __syncthreads();

        for (int t = 0; t < 8; ++t) {
            const int cur = t & 1;
            const __bf16* Ks = cur ? Ke1 : Ke0;
            unsigned long long kbits = kb_next;

            f32x4 acc[4];
            __builtin_amdgcn_s_setprio(1);
#pragma unroll
            for (int kb = 0; kb < 4; ++kb) {
                bf16x8 af[4];
#pragma unroll
                for (int kf = 0; kf < 4; ++kf)
                    af[kf] = *(const bf16x8*)(Ks + (kb * 16 + fr) * 136 + kf * 32 + fq * 8);
                f32x4 a = {};
#pragma unroll
                for (int kf = 0; kf < 4; ++kf)
                    a = __builtin_amdgcn_mfma_f32_16x16x32_bf16(af[kf], qf[kf], a, 0, 0, 0);
                acc[kb] = a;
            }
            __builtin_amdgcn_s_setprio(0);

#pragma unroll
            for (int kb = 0; kb < 4; ++kb) {
                f32x4 pj = *(const f32x4*)(posg + t * 64 + kb * 16 + fq * 4);
#pragma unroll
                for (int r = 0; r < 4; ++r) {
                    float di = qposf - pj[r];
                    acc[kb][r] -= sft * di * di;
                }
            }

            float lmax = acc[0][0];
#pragma unroll
            for (int kb = 0; kb < 4; ++kb)
#pragma unroll
                for (int r = 0; r < 4; ++r) lmax = fmaxf(lmax, acc[kb][r]);
            if (!__all(lmax <= mrun + 8.f)) {
                float mn = fmaxf(mrun, lmax);
                mn = fmaxf(mn, __shfl_xor(mn, 16));
                mn = fmaxf(mn, __shfl_xor(mn, 32));
                float sc = __expf(mrun - mn);
                mrun = mn;
                lrun *= sc;
#pragma unroll
                for (int fd = 0; fd < 4; ++fd)
#pragma unroll
                    for (int r = 0; r < 4; ++r) ot[fd][r] *= sc;
            }
            float sum = 0.f;
#pragma unroll
            for (int kb = 0; kb < 4; ++kb)
#pragma unroll
                for (int r = 0; r < 4; ++r) {
                    int ko = kb * 16 + fq * 4 + r;
                    float p = ((int)(kbits >> ko) & 1) ? __expf(acc[kb][r] - mrun) : 0.f;
                    acc[kb][r] = p;
                    sum += p;
                }
            lrun += sum;   // lane-partial; reduced once after the loop

            __builtin_amdgcn_s_setprio(1);
#pragma unroll
            for (int half = 0; half < 2; ++half) {
#pragma unroll
                for (int kk = 0; kk < 2; ++kk) {
                    int kb = half * 2 + kk;
                    bf16x4 pk;
#pragma unroll
                    for (int r = 0; r < 4; ++r) pk[r] = (__bf16)acc[kb][r];
                    *(bf16x4*)(Sw + fr * 40 + kk * 16 + fq * 4) = pk;
                }
                bf16x8 pf = *(const bf16x8*)(Sw + fr * 40 + fq * 8);
#pragma unroll
                for (int fd = 0; fd < 4; ++fd) {
                    bf16x8 vf = *(const bf16x8*)(Vts[cur] + (fd * 16 + fr) * 72 + half * 32 + fq * 8);
                    ot[fd] = __builtin_amdgcn_mfma_f32_16x16x32_bf16(vf, pf, ot[fd], 0, 0, 0);
                }
            }
            __builtin_amdgcn_s_setprio(0);

            if (t < 7) {
                STAGEP(cur ^ 1);
                kb_next = __ballot(pm != 0);
                if (t < 6) LOADP(t + 2);
                __syncthreads();
            }
        }
#undef LOADP
#undef STAGEP
    } else {
        // ===== MIXED: 8 tiles x 64 keys, both variants, 2 barriers/tile =====
        bf16x8 rk0[2], rk1[2], rv;
        int pm;

#define LOADM(tt)                                                                  \
    {                                                                              \
        int j0_ = (tt) * 64;                                                       \
        _Pragma("unroll")                                                          \
        for (int p = 0; p < 2; ++p) {                                              \
            int sr = j0_ + p * 32 + krr;                                           \
            int orow = perm[b * LL + sr];                                          \
            int qmj = (sr >= nz) ? 1 : 0;                                          \
            const __bf16* s1 = (qmj ? K2g0 : K1g0) + (size_t)orow * 128 + ku * 8;  \
            const __bf16* s2 = (qmj ? K1g0 : K2g0) + (size_t)orow * 128 + ku * 8;  \
            rk0[p] = *(const bf16x8*)s1;                                           \
            rk1[p] = *(const bf16x8*)s2;                                           \
        }                                                                          \
        rv = *(const bf16x8*)(Vtg0 + (size_t)vrr * LL + j0_ + vu * 8);             \
        pm = pmask[b * LL + j0_ + lane];                                           \
    }

        LOADM(0);
        for (int t = 0; t < 8; ++t) {
            __syncthreads();
            {
#pragma unroll
                for (int p = 0; p < 2; ++p) {
                    int rr = p * 32 + krr;
                    *(bf16x8*)(Ke0 + rr * 136 + ku * 8) = rk0[p];
                    *(bf16x8*)(Ke1 + rr * 136 + ku * 8) = rk1[p];
                }
                *(bf16x8*)(Vts[0] + vrr * 72 + vu * 8) = rv;
            }
            unsigned long long kbits = __ballot(pm != 0);
            if (t < 7) LOADM(t + 1);
            __syncthreads();

            f32x4 acc[4];
            if (wneed0 != wneed1) {
                const __bf16* Ks = wneed0 ? Ke0 : Ke1;
                __builtin_amdgcn_s_setprio(1);
#pragma unroll
                for (int kb = 0; kb < 4; ++kb) {
                    bf16x8 af[4];
#pragma unroll
                    for (int kf = 0; kf < 4; ++kf)
                        af[kf] = *(const bf16x8*)(Ks + (kb * 16 + fr) * 136 + kf * 32 + fq * 8);
                    f32x4 a = {};
#pragma unroll
                    for (int kf = 0; kf < 4; ++kf)
                        a = __builtin_amdgcn_mfma_f32_16x16x32_bf16(af[kf], qf[kf], a, 0, 0, 0);
                    acc[kb] = a;
                }
                __builtin_amdgcn_s_setprio(0);
            } else {
                __builtin_amdgcn_s_setprio(1);
#pragma unroll
                for (int kb = 0; kb < 4; ++kb) {
                    bf16x8 a0f[4], a1f[4];
#pragma unroll
                    for (int kf = 0; kf < 4; ++kf) {
                        a0f[kf] = *(const bf16x8*)(Ke0 + (kb * 16 + fr) * 136 + kf * 32 + fq * 8);
                        a1f[kf] = *(const bf16x8*)(Ke1 + (kb * 16 + fr) * 136 + kf * 32 + fq * 8);
                    }
                    f32x4 t0 = {}, t1 = {};
#pragma unroll
                    for (int kf = 0; kf < 4; ++kf) {
                        t0 = __builtin_amdgcn_mfma_f32_16x16x32_bf16(a0f[kf], qf[kf], t0, 0, 0, 0);
                        t1 = __builtin_amdgcn_mfma_f32_16x16x32_bf16(a1f[kf], qf[kf], t1, 0, 0, 0);
                    }
#pragma unroll
                    for (int r = 0; r < 4; ++r) acc[kb][r] = qmI ? t1[r] : t0[r];
                }
                __builtin_amdgcn_s_setprio(0);
            }

#pragma unroll
            for (int kb = 0; kb < 4; ++kb) {
                f32x4 pj = *(const f32x4*)(posg + t * 64 + kb * 16 + fq * 4);
#pragma unroll
                for (int r = 0; r < 4; ++r) {
                    float di = qposf - pj[r];
                    acc[kb][r] -= sft * di * di;
                }
            }

            float lmax = acc[0][0];
#pragma unroll
            for (int kb = 0; kb < 4; ++kb)
#pragma unroll
                for (int r = 0; r < 4; ++r) lmax = fmaxf(lmax, acc[kb][r]);
            if (!__all(lmax <= mrun + 8.f)) {
                float mn = fmaxf(mrun, lmax);
                mn = fmaxf(mn, __shfl_xor(mn, 16));
                mn = fmaxf(mn, __shfl_xor(mn, 32));
                float sc = __expf(mrun - mn);
                mrun = mn;
                lrun *= sc;
#pragma unroll
                for (int fd = 0; fd < 4; ++fd)
#pragma unroll
                    for (int r = 0; r < 4; ++r) ot[fd][r] *= sc;
            }
            float sum = 0.f;
#pragma unroll
            for (int kb = 0; kb < 4; ++kb)
#pragma unroll
                for (int r = 0; r < 4; ++r) {
                    int ko = kb * 16 + fq * 4 + r;
                    float p = ((int)(kbits >> ko) & 1) ? __expf(acc[kb][r] - mrun) : 0.f;
                    acc[kb][r] = p;
                    sum += p;
                }
            lrun += sum;   // lane-partial

            __builtin_amdgcn_s_setprio(1);
#pragma unroll
            for (int half = 0; half < 2; ++half) {
#pragma unroll
                for (int kk = 0; kk < 2; ++kk) {
                    int kb = half * 2 + kk;
                    bf16x4 pk;
#pragma unroll
                    for (int r = 0; r < 4; ++r) pk[r] = (__bf16)acc[kb][r];
                    *(bf16x4*)(Sw + fr * 40 + kk * 16 + fq * 4) = pk;
                }
                bf16x8 pf = *(const bf16x8*)(Sw + fr * 40 + fq * 8);
#pragma unroll
                for (int fd = 0; fd < 4; ++fd) {
                    bf16x8 vf = *(const bf16x8*)(Vts[0] + (fd * 16 + fr) * 72 + half * 32 + fq * 8);
                    ot[fd] = __builtin_amdgcn_mfma_f32_16x16x32_bf16(vf, pf, ot[fd], 0, 0, 0);
                }
            }
            __builtin_amdgcn_s_setprio(0);
        }
#undef LOADM
    }

    // ---- final cross-lane lrun reduce (moved out of the tile loop) ----
    lrun += __shfl_xor(lrun, 16);
    lrun += __shfl_xor(lrun, 32);

    // ---- epilogue: O -> dead Ke0 (flat [128][72]) -> coalesced scatter via perm ----
    __syncthreads();
    {
        const float inv = 1.0f / lrun;
        __bf16* Ew = Ke0 + (size_t)(wid * 16) * 72;
#pragma unroll
        for (int fd = 0; fd < 4; ++fd) {
            bf16x4 o;
#pragma unroll
            for (int r = 0; r < 4; ++r) o[r] = (__bf16)(ot[fd][r] * inv);
            *(bf16x4*)(Ew + fr * 72 + fd * 16 + fq * 4) = o;
        }
    }
    __syncthreads();
    {
        int r = tid >> 2, c = tid & 3;
        int pir = perm[b * LL + q0blk + r];
        const __bf16* src = Ke0 + (size_t)r * 72;
        __bf16* dst = AO + ((size_t)(b * LL + pir)) * DM + h * 64;
        *(bf16x8*)(dst + c * 8)      = *(const bf16x8*)(src + c * 8);
        *(bf16x8*)(dst + 32 + c * 8) = *(const bf16x8*)(src + 32 + c * 8);
    }
}

extern "C" void kernel_launch(void* const* d_in, const int* in_sizes, int n_in,
                              void* d_out, int out_size, void* d_ws, size_t ws_size,
                              hipStream_t stream) {
    const float* x     = (const float*)d_in[0];
    const int*   mask  = (const int*)d_in[1];
    const int*   qmask = (const int*)d_in[2];
    const float* W_qkv = (const float*)d_in[3];
    const float* W_pos = (const float*)d_in[4];
    const float* W_fc  = (const float*)d_in[5];
    const float* b_fc  = (const float*)d_in[6];
    const float* shift = (const float*)d_in[7];
    const float* bias  = (const float*)d_in[8];
    float* out = (float*)d_out;

    __bf16* Qcb  = (__bf16*)d_ws;           // [8,16,512,128]
    __bf16* K1cb = Qcb  + 8388608;
    __bf16* K2cb = K1cb + 8388608;
    __bf16* Vnb  = K2cb + 8388608;          // [8,16,512,64]
    __bf16* Vtb  = Vnb  + 4194304;          // [8,16,64,512] (key-permuted)
    __bf16* Xb   = Vtb  + 4194304;          // [4096,1024]
    __bf16* Wqkvb = Xb  + 4194304;          // [4096,1024] remapped
    __bf16* AOb   = Xb;                     // alias (attn writes after gemm reads)
    __bf16* PEb   = Wqkvb + 4194304;        // [512,64] bf16
    __bf16* Wposb = PEb + 32768;            // [3072,64] bf16
    __bf16* Wfcb  = Wposb + 196608;         // [1024,1024] bf16
    int* permA = (int*)(Wfcb + 1048576);    // [8,512]
    int* nzA   = permA + 4096;              // [8]
    int* pmaskA = nzA + 8;                  // [8,512]
    float* posfA = (float*)(pmaskA + 4096); // [8,512]
    int* schedA = (int*)(posfA + 4096);     // [512]

    prep_kernel<<<2424, 512, 0, stream>>>(qmask, mask, x, W_qkv, W_pos, W_fc,
                                          permA, pmaskA, posfA, nzA, schedA,
                                          PEb, Wposb, Wfcb, Xb, Wqkvb);
    gemm_fused<<<1120, 256, 0, stream>>>(Xb, Wqkvb, PEb, Wposb,
                                         Qcb, K1cb, K2cb, Vnb);
    vtrans_kernel<<<1024, 256, 0, stream>>>(Vnb, permA, Vtb);
    attn_kernel<<<512, 512, 0, stream>>>(Qcb, K1cb, K2cb, Vtb, pmaskA, permA,
                                         posfA, nzA, schedA, shift, AOb);
    gemm_out<<<dim3(8, 32), 256, 0, stream>>>(AOb, Wfcb, out, b_fc);
}

// Round 20
// 122.941 us; speedup vs baseline: 1.0111x; 1.0111x over previous
//
#include <hip/hip_runtime.h>

#define DM 1024
#define HN 16
#define HD 64
#define BB 8
#define LL 512

typedef __bf16 bf16x8 __attribute__((ext_vector_type(8)));
typedef __bf16 bf16x4 __attribute__((ext_vector_type(4)));
typedef float  f32x4  __attribute__((ext_vector_type(4)));

__device__ __forceinline__ void cvt8(const float* __restrict__ in,
                                     __bf16* __restrict__ out, int i) {
    const float4* p = (const float4*)in + (size_t)i * 2;
    float4 a = p[0], b = p[1];
    bf16x8 v;
    v[0] = (__bf16)a.x; v[1] = (__bf16)a.y; v[2] = (__bf16)a.z; v[3] = (__bf16)a.w;
    v[4] = (__bf16)b.x; v[5] = (__bf16)b.y; v[6] = (__bf16)b.z; v[7] = (__bf16)b.w;
    ((bf16x8*)out)[i] = v;
}

// ---------------- fused prep: sortq + schedule + PE + all f32->bf16 cvts -------
__global__ __launch_bounds__(512) void prep_kernel(
    const int* __restrict__ qmask, const int* __restrict__ maskp,
    const float* __restrict__ x, const float* __restrict__ W_qkv,
    const float* __restrict__ W_pos, const float* __restrict__ W_fc,
    int* __restrict__ perm, int* __restrict__ pmask, float* __restrict__ posf,
    int* __restrict__ nzA, int* __restrict__ sched,
    __bf16* __restrict__ PEb, __bf16* __restrict__ Wposb,
    __bf16* __restrict__ Wfcb, __bf16* __restrict__ Xb, __bf16* __restrict__ Wqkvb)
{
    const int blk = blockIdx.x, tid = threadIdx.x;
    if (blk < 8) {                       // ---- sortq + schedule ----
        int b = blk, i = tid;
        int qm = qmask[b * LL + i];
        unsigned long long bz = __ballot(qm == 0);
        int wid = i >> 6, lane = i & 63;
        __shared__ int wz[8];
        int pzw = __popcll(bz & ((1ULL << lane) - 1ULL));
        if (lane == 0) wz[wid] = __popcll(bz);
        __syncthreads();
        int base = 0, nz = 0;
#pragma unroll
        for (int w2 = 0; w2 < 8; ++w2) { int c = wz[w2]; if (w2 < wid) base += c; nz += c; }
        int zbefore = base + pzw;
        int pos = (qm == 0) ? zbefore : (nz + (i - zbefore));
        perm[b * LL + pos] = i;
        pmask[b * LL + pos] = maskp[b * LL + i];
        posf[b * LL + pos] = (float)i;
        if (i == 0) nzA[b] = nz;
        if (i < 16) {                    // mixed qt first per XCD group
            int bh2 = b * 16 + i;
            int g = i & 7;
            int idx = b * 2 + (i >> 3);
            int qtm = nz >> 7; if (qtm > 3) qtm = 3;
            sched[idx * 8 + g] = (bh2 << 2) | qtm;
#pragma unroll
            for (int j = 0; j < 3; ++j) {
                int qtj = j + (j >= qtm ? 1 : 0);
                sched[(16 + idx * 3 + j) * 8 + g] = (bh2 << 2) | qtj;
            }
        }
    } else if (blk < 72) {               // ---- PE table [512][64] bf16 ----
        int idx = (blk - 8) * 512 + tid;
        int l = idx >> 6, d = idx & 63;
        float p = (float)(l - LL / 2);
        const float cexp = -9.210340371976184f / 31.0f;
        float val;
        if (d < 32) { float f = expf((float)d * cexp);        val = sinf(p * f); }
        else        { float f = expf((float)(d - 32) * cexp); val = cosf(p * f); }
        PEb[idx] = (__bf16)val;
    } else if (blk < 120) {
        cvt8(W_pos, Wposb, (blk - 72) * 512 + tid);
    } else if (blk < 376) {
        cvt8(W_fc, Wfcb, (blk - 120) * 512 + tid);
    } else if (blk < 1400) {
        cvt8(x, Xb, (blk - 376) * 512 + tid);
    } else if (blk < 1656) {
        cvt8(W_qkv, Wqkvb, (blk - 1400) * 512 + tid);
    } else {
        cvt8(W_qkv + 2097152, Wqkvb + 1048576, (blk - 1656) * 512 + tid);
    }
}

// ------- fused QKV + pos-proj GEMM (r17-proven) ----
__global__ __launch_bounds__(256, 4) void gemm_fused(
    const __bf16* __restrict__ Xb, const __bf16* __restrict__ Wqkvb,
    const __bf16* __restrict__ PEb, const __bf16* __restrict__ Wposb,
    __bf16* __restrict__ Qc, __bf16* __restrict__ K1c,
    __bf16* __restrict__ K2c, __bf16* __restrict__ Vn)
{
    __shared__ __bf16 smem[128 * 136];
    __bf16* As = smem;
    __bf16* Bs = smem + 8192;
    __bf16* Cs = smem;
    const int tid = threadIdx.x;
    const int lane = tid & 63;
    const int w = tid >> 6;
    const int wm = w >> 1, wn = w & 1;

    const bool isPos = (blockIdx.x >= 1024);
    const int bi = isPos ? (blockIdx.x - 1024) : blockIdx.x;
    const int n0 = isPos ? (bi % 24) * 128 : (bi & 31) * 128;
    const int m0 = isPos ? (bi / 24) * 128 : (bi >> 5) * 128;
    const int K  = isPos ? 64 : 1024;
    const __bf16* A  = isPos ? PEb : Xb;
    const __bf16* Bm = isPos ? Wposb : Wqkvb;

    const int fr = lane & 15;
    const int fq = lane >> 4;

    const int srow = tid >> 3;
    const int scol = (tid & 7) ^ (srow & 7);
    const __bf16* Ag = A + (size_t)(m0 + srow) * K + scol * 8;
    const __bf16* Bg = Bm + (size_t)(n0 + srow) * K + scol * 8;
    char* AsB = (char*)As + (size_t)w * 1024;
    char* BsB = (char*)Bs + (size_t)w * 1024;

    f32x4 acc[4][4] = {};

    for (int k0 = 0; k0 < K; k0 += 64) {
#pragma unroll
        for (int r = 0; r < 4; ++r) {
            __builtin_amdgcn_global_load_lds(Ag + k0 + (size_t)(r * 32) * K, AsB + r * 4096, 16, 0, 0);
            __builtin_amdgcn_global_load_lds(Bg + k0 + (size_t)(r * 32) * K, BsB + r * 4096, 16, 0, 0);
        }
        __syncthreads();

#pragma unroll
        for (int kk = 0; kk < 2; ++kk) {
            const int so = ((kk * 4 + fq) ^ (fr & 7)) * 8;
            bf16x8 af[4], bfr[4];
#pragma unroll
            for (int i = 0; i < 4; ++i)
                af[i] = *(const bf16x8*)(As + (size_t)(wm * 64 + i * 16 + fr) * 64 + so);
#pragma unroll
            for (int j = 0; j < 4; ++j)
                bfr[j] = *(const bf16x8*)(Bs + (size_t)(wn * 64 + j * 16 + fr) * 64 + so);
#pragma unroll
            for (int i = 0; i < 4; ++i)
#pragma unroll
                for (int j = 0; j < 4; ++j)
                    acc[i][j] = __builtin_amdgcn_mfma_f32_16x16x32_bf16(bfr[j], af[i], acc[i][j], 0, 0, 0);
        }
        __syncthreads();
    }

#pragma unroll
    for (int i = 0; i < 4; ++i) {
        int mloc = wm * 64 + i * 16 + fr;
#pragma unroll
        for (int j = 0; j < 4; ++j) {
            int nloc = wn * 64 + j * 16 + fq * 4;
            bf16x4 v;
#pragma unroll
            for (int r = 0; r < 4; ++r) v[r] = (__bf16)acc[i][j][r];
            *(bf16x4*)(Cs + (size_t)mloc * 136 + nloc) = v;
        }
    }
    __syncthreads();
    if (!isPos) {
        const int c = n0 >> 10;
        __bf16* T = (c == 0) ? Qc : (c == 1) ? K1c : (c == 2) ? K2c : Vn;
        const int b = m0 >> 9, l0 = m0 & 511, h0 = (n0 >> 6) & 15;
#pragma unroll
        for (int rnd = 0; rnd < 8; ++rnd) {
            int Ci = rnd * 256 + tid;
            int m = Ci >> 4, nch = Ci & 15;
            bf16x8 v = *(const bf16x8*)(Cs + (size_t)m * 136 + nch * 8);
            int hl = nch >> 3, d = (nch & 7) * 8;
            size_t bh2 = (size_t)(b * HN + h0 + hl);
            if (c < 3) *(bf16x8*)(T + (bh2 * LL + l0 + m) * 128 + d) = v;
            else       *(bf16x8*)(T + (bh2 * LL + l0 + m) * 64  + d) = v;
        }
    } else {
        const int c = n0 >> 10;
        __bf16* T = (c == 0) ? Qc : (c == 1) ? K1c : K2c;
#pragma unroll
        for (int rnd = 0; rnd < 8; ++rnd) {
            int Ci = rnd * 256 + tid;
            int m = Ci >> 4, nch = Ci & 15;
            bf16x8 v = *(const bf16x8*)(Cs + (size_t)m * 136 + nch * 8);
            int eg = n0 + nch * 8;
            int h = (eg >> 6) & 15, d = eg & 63;
            size_t off = ((size_t)h * LL + (m0 + m)) * 128 + 64 + d;
#pragma unroll
            for (int b = 0; b < 8; ++b)
                *(bf16x8*)(T + (size_t)b * (HN * LL * 128) + off) = v;
        }
    }
}

// ---------------- out-proj GEMM ----------------
__global__ __launch_bounds__(256, 4) void gemm_out(
    const __bf16* __restrict__ A, const __bf16* __restrict__ Bm,
    float* __restrict__ outF, const float* __restrict__ bias)
{
    __shared__ __bf16 smem[128 * 136];
    __bf16* As = smem;
    __bf16* Bs = smem + 8192;
    const int tid = threadIdx.x;
    const int lane = tid & 63;
    const int w = tid >> 6;
    const int wm = w >> 1, wn = w & 1;
    const int n0 = blockIdx.x * 128;
    const int m0 = blockIdx.y * 128;
    const int fr = lane & 15;
    const int fq = lane >> 4;
    const int K = 1024;

    const int srow = tid >> 3;
    const int scol = (tid & 7) ^ (srow & 7);
    const __bf16* Ag = A + (size_t)(m0 + srow) * K + scol * 8;
    const __bf16* Bg = Bm + (size_t)(n0 + srow) * K + scol * 8;
    char* AsB = (char*)As + (size_t)w * 1024;
    char* BsB = (char*)Bs + (size_t)w * 1024;

    f32x4 acc[4][4] = {};

    for (int k0 = 0; k0 < K; k0 += 64) {
#pragma unroll
        for (int r = 0; r < 4; ++r) {
            __builtin_amdgcn_global_load_lds(Ag + k0 + (size_t)(r * 32) * K, AsB + r * 4096, 16, 0, 0);
            __builtin_amdgcn_global_load_lds(Bg + k0 + (size_t)(r * 32) * K, BsB + r * 4096, 16, 0, 0);
        }
        __syncthreads();

#pragma unroll
        for (int kk = 0; kk < 2; ++kk) {
            const int so = ((kk * 4 + fq) ^ (fr & 7)) * 8;
            bf16x8 af[4], bfr[4];
#pragma unroll
            for (int i = 0; i < 4; ++i)
                af[i] = *(const bf16x8*)(As + (size_t)(wm * 64 + i * 16 + fr) * 64 + so);
#pragma unroll
            for (int j = 0; j < 4; ++j)
                bfr[j] = *(const bf16x8*)(Bs + (size_t)(wn * 64 + j * 16 + fr) * 64 + so);
#pragma unroll
            for (int i = 0; i < 4; ++i)
#pragma unroll
                for (int j = 0; j < 4; ++j)
                    acc[i][j] = __builtin_amdgcn_mfma_f32_16x16x32_bf16(bfr[j], af[i], acc[i][j], 0, 0, 0);
        }
        __syncthreads();
    }

#pragma unroll
    for (int i = 0; i < 4; ++i) {
        int m = m0 + wm * 64 + i * 16 + fr;
#pragma unroll
        for (int j = 0; j < 4; ++j) {
            int nn = n0 + wn * 64 + j * 16 + fq * 4;
            float4 bv = *(const float4*)(bias + nn);
            *(float4*)(outF + (size_t)m * DM + nn) =
                make_float4(acc[i][j][0] + bv.x, acc[i][j][1] + bv.y,
                            acc[i][j][2] + bv.z, acc[i][j][3] + bv.w);
        }
    }
}

// -------- V transpose + key permute -------
__global__ __launch_bounds__(256) void vtrans_kernel(const __bf16* __restrict__ Vn,
                                                     const int* __restrict__ perm,
                                                     __bf16* __restrict__ Vt) {
    __shared__ __bf16 Ts[64][72];
    int bh = blockIdx.x >> 3, lt = blockIdx.x & 7;
    int b = bh >> 4;
    int r = threadIdx.x >> 2, s = threadIdx.x & 3;
    int orow = perm[b * LL + lt * 64 + r];
    const __bf16* src = Vn + ((size_t)bh * LL + orow) * 64;
    *(bf16x8*)&Ts[r][s * 16]     = *(const bf16x8*)(src + s * 16);
    *(bf16x8*)&Ts[r][s * 16 + 8] = *(const bf16x8*)(src + s * 16 + 8);
    __syncthreads();
    __bf16* dst = Vt + ((size_t)bh * 64 + r) * LL + lt * 64 + s * 16;
    bf16x8 a, bvv;
#pragma unroll
    for (int e = 0; e < 8; ++e) { a[e] = Ts[s * 16 + e][r]; bvv[e] = Ts[s * 16 + 8 + e][r]; }
    *(bf16x8*)dst = a;
    *(bf16x8*)(dst + 8) = bvv;
}

// ------- MFMA flash attention: PURE blocks = single-barrier double-buffered
// (Ke halves = 2 tile buffers, Vts[2], loads 2 tiles ahead); MIXED = r15 path.
// Sb [16][40] two-half PV; epilogue via dead Ke. LDS total 64,000 B.
// (r18-exact: r19's lane-partial lrun + posf-direct were measured neutral-negative
// with conflicts invariant at 4.096M -- reverted.)
__global__ __launch_bounds__(512, 2) void attn_kernel(
    const __bf16* __restrict__ Qc, const __bf16* __restrict__ K1c,
    const __bf16* __restrict__ K2c, const __bf16* __restrict__ Vt,
    const int* __restrict__ pmask, const int* __restrict__ perm,
    const float* __restrict__ posf, const int* __restrict__ nzA,
    const int* __restrict__ sched,
    const float* __restrict__ shiftp, __bf16* __restrict__ AO)
{
    __shared__ __bf16 Ke0[64 * 136];
    __shared__ __bf16 Ke1[64 * 136];
    __shared__ __bf16 Vts[2][64 * 72];
    __shared__ __bf16 Sb[8 * 16 * 40];
    __shared__ __align__(16) float posL[2][64];

    const int tid = threadIdx.x;
    const int lane = tid & 63;
    const int wid = tid >> 6;
    const int fr = lane & 15;
    const int fq = lane >> 4;

    const int e = sched[blockIdx.x];
    const int qt = e & 3;
    const int h  = (e >> 2) & 15;
    const int b  = e >> 6;
    const size_t bh = (size_t)(b * HN + h);
    const int nz = nzA[b];
    const int q0blk = qt * 128;
    const int s = q0blk + wid * 16 + fr;
    const int pi = perm[b * LL + s];
    const bool need0 = (q0blk < nz);
    const bool need1 = (q0blk + 127 >= nz);
    const int w0 = q0blk + wid * 16;
    const bool wneed0 = (w0 < nz);
    const bool wneed1 = (w0 + 15 >= nz);
    const int qmI = (s >= nz) ? 1 : 0;

    const float sft = shiftp[0];

    bf16x8 qf[4];
    {
        const __bf16* qrow = Qc + (bh * LL + pi) * 128;
#pragma unroll
        for (int kf = 0; kf < 4; ++kf)
            qf[kf] = *(const bf16x8*)(qrow + kf * 32 + fq * 8);
    }

    float mrun = -1e30f, lrun = 0.f;
    f32x4 ot[4] = {};
    const float qposf = (float)pi;

    const __bf16* K1g0 = K1c + bh * LL * 128;
    const __bf16* K2g0 = K2c + bh * LL * 128;
    const __bf16* Vtg0 = Vt + bh * 64 * LL;
    __bf16* Sw = Sb + wid * 16 * 40;

    const int krr = tid >> 4;      // 0..31
    const int ku  = tid & 15;
    const int vrr = tid >> 3;      // 0..63
    const int vu  = tid & 7;

    if (!(need0 && need1)) {
        // ===== PURE: 8 tiles x 64 keys, double-buffered, ONE barrier/tile =====
        const __bf16* KA = need0 ? K1g0 : K2g0;
        const __bf16* KB = need0 ? K2g0 : K1g0;
        bf16x8 rk[2], rv;
        int pm; float ppos;

#define LOADP(tt)                                                                  \
    {                                                                              \
        int j0_ = (tt) * 64;                                                       \
        _Pragma("unroll")                                                          \
        for (int p = 0; p < 2; ++p) {                                              \
            int sr = j0_ + p * 32 + krr;                                           \
            int orow = perm[b * LL + sr];                                          \
            rk[p] = *(const bf16x8*)(((sr >= nz) ? KB : KA) + (size_t)orow * 128 + ku * 8); \
        }                                                                          \
        rv = *(const bf16x8*)(Vtg0 + (size_t)vrr * LL + j0_ + vu * 8);             \
        pm = pmask[b * LL + j0_ + lane];                                           \
        ppos = posf[b * LL + j0_ + lane];                                          \
    }

#define STAGEP(buf)                                                                \
    {                                                                              \
        __bf16* Kd = (buf) ? Ke1 : Ke0;                                            \
        _Pragma("unroll")                                                          \
        for (int p = 0; p < 2; ++p) {                                              \
            int rr = p * 32 + krr;                                                 \
            *(bf16x8*)(Kd + rr * 136 + ku * 8) = rk[p];                            \
        }                                                                          \
        *(bf16x8*)(Vts[buf] + vrr * 72 + vu * 8) = rv;                             \
        if (wid == 0) posL[buf][lane] = ppos;                                      \
    }

        LOADP(0);
        STAGEP(0);
        unsigned long long kb_next = __ballot(pm != 0);
        LOADP(1);
        __syncthreads();

        for (int t = 0; t < 8; ++t) {
            const int cur = t & 1;
            const __bf16* Ks = cur ? Ke1 : Ke0;
            unsigned long long kbits = kb_next;

            f32x4 acc[4];
            __builtin_amdgcn_s_setprio(1);
#pragma unroll
            for (int kb = 0; kb < 4; ++kb) {
                bf16x8 af[4];
#pragma unroll
                for (int kf = 0; kf < 4; ++kf)
                    af[kf] = *(const bf16x8*)(Ks + (kb * 16 + fr) * 136 + kf * 32 + fq * 8);
                f32x4 a = {};
#pragma unroll
                for (int kf = 0; kf < 4; ++kf)
                    a = __builtin_amdgcn_mfma_f32_16x16x32_bf16(af[kf], qf[kf], a, 0, 0, 0);
                acc[kb] = a;
            }
            __builtin_amdgcn_s_setprio(0);

#pragma unroll
            for (int kb = 0; kb < 4; ++kb) {
                f32x4 pj = *(const f32x4*)(&posL[cur][kb * 16 + fq * 4]);
#pragma unroll
                for (int r = 0; r < 4; ++r) {
                    float di = qposf - pj[r];
                    acc[kb][r] -= sft * di * di;
                }
            }

            float lmax = acc[0][0];
#pragma unroll
            for (int kb = 0; kb < 4; ++kb)
#pragma unroll
                for (int r = 0; r < 4; ++r) lmax = fmaxf(lmax, acc[kb][r]);
            if (!__all(lmax <= mrun + 8.f)) {
                float mn = fmaxf(mrun, lmax);
                mn = fmaxf(mn, __shfl_xor(mn, 16));
                mn = fmaxf(mn, __shfl_xor(mn, 32));
                float sc = __expf(mrun - mn);
                mrun = mn;
                lrun *= sc;
#pragma unroll
                for (int fd = 0; fd < 4; ++fd)
#pragma unroll
                    for (int r = 0; r < 4; ++r) ot[fd][r] *= sc;
            }
            float sum = 0.f;
#pragma unroll
            for (int kb = 0; kb < 4; ++kb)
#pragma unroll
                for (int r = 0; r < 4; ++r) {
                    int ko = kb * 16 + fq * 4 + r;
                    float p = ((int)(kbits >> ko) & 1) ? __expf(acc[kb][r] - mrun) : 0.f;
                    acc[kb][r] = p;
                    sum += p;
                }
            sum += __shfl_xor(sum, 16);
            sum += __shfl_xor(sum, 32);
            lrun += sum;

            // two-half PV through per-wave Sw [16][40]
            __builtin_amdgcn_s_setprio(1);
#pragma unroll
            for (int half = 0; half < 2; ++half) {
#pragma unroll
                for (int kk = 0; kk < 2; ++kk) {
                    int kb = half * 2 + kk;
                    bf16x4 pk;
#pragma unroll
                    for (int r = 0; r < 4; ++r) pk[r] = (__bf16)acc[kb][r];
                    *(bf16x4*)(Sw + fr * 40 + kk * 16 + fq * 4) = pk;
                }
                bf16x8 pf = *(const bf16x8*)(Sw + fr * 40 + fq * 8);
#pragma unroll
                for (int fd = 0; fd < 4; ++fd) {
                    bf16x8 vf = *(const bf16x8*)(Vts[cur] + (fd * 16 + fr) * 72 + half * 32 + fq * 8);
                    ot[fd] = __builtin_amdgcn_mfma_f32_16x16x32_bf16(vf, pf, ot[fd], 0, 0, 0);
                }
            }
            __builtin_amdgcn_s_setprio(0);

            if (t < 7) {
                STAGEP(cur ^ 1);              // regs hold tile t+1
                kb_next = __ballot(pm != 0);
                if (t < 6) LOADP(t + 2);      // 2-deep prefetch
                __syncthreads();              // ONE barrier per tile
            }
        }
#undef LOADP
#undef STAGEP
    } else {
        // ===== MIXED: 8 tiles x 64 keys, both variants, 2 barriers/tile =====
        bf16x8 rk0[2], rk1[2], rv;
        int pm; float ppos;

#define LOADM(tt)                                                                  \
    {                                                                              \
        int j0_ = (tt) * 64;                                                       \
        _Pragma("unroll")                                                          \
        for (int p = 0; p < 2; ++p) {                                              \
            int sr = j0_ + p * 32 + krr;                                           \
            int orow = perm[b * LL + sr];                                          \
            int qmj = (sr >= nz) ? 1 : 0;                                          \
            const __bf16* s1 = (qmj ? K2g0 : K1g0) + (size_t)orow * 128 + ku * 8;  \
            const __bf16* s2 = (qmj ? K1g0 : K2g0) + (size_t)orow * 128 + ku * 8;  \
            rk0[p] = *(const bf16x8*)s1;                                           \
            rk1[p] = *(const bf16x8*)s2;                                           \
        }                                                                          \
        rv = *(const bf16x8*)(Vtg0 + (size_t)vrr * LL + j0_ + vu * 8);             \
        pm = pmask[b * LL + j0_ + lane];                                           \
        ppos = posf[b * LL + j0_ + lane];                                          \
    }

        LOADM(0);
        for (int t = 0; t < 8; ++t) {
            __syncthreads();
            {
#pragma unroll
                for (int p = 0; p < 2; ++p) {
                    int rr = p * 32 + krr;
                    *(bf16x8*)(Ke0 + rr * 136 + ku * 8) = rk0[p];
                    *(bf16x8*)(Ke1 + rr * 136 + ku * 8) = rk1[p];
                }
                *(bf16x8*)(Vts[0] + vrr * 72 + vu * 8) = rv;
                if (wid == 0) posL[0][lane] = ppos;
            }
            unsigned long long kbits = __ballot(pm != 0);
            if (t < 7) LOADM(t + 1);
            __syncthreads();

            f32x4 acc[4];
            if (wneed0 != wneed1) {
                const __bf16* Ks = wneed0 ? Ke0 : Ke1;
                __builtin_amdgcn_s_setprio(1);
#pragma unroll
                for (int kb = 0; kb < 4; ++kb) {
                    bf16x8 af[4];
#pragma unroll
                    for (int kf = 0; kf < 4; ++kf)
                        af[kf] = *(const bf16x8*)(Ks + (kb * 16 + fr) * 136 + kf * 32 + fq * 8);
                    f32x4 a = {};
#pragma unroll
                    for (int kf = 0; kf < 4; ++kf)
                        a = __builtin_amdgcn_mfma_f32_16x16x32_bf16(af[kf], qf[kf], a, 0, 0, 0);
                    acc[kb] = a;
                }
                __builtin_amdgcn_s_setprio(0);
            } else {
                __builtin_amdgcn_s_setprio(1);
#pragma unroll
                for (int kb = 0; kb < 4; ++kb) {
                    bf16x8 a0f[4], a1f[4];
#pragma unroll
                    for (int kf = 0; kf < 4; ++kf) {
                        a0f[kf] = *(const bf16x8*)(Ke0 + (kb * 16 + fr) * 136 + kf * 32 + fq * 8);
                        a1f[kf] = *(const bf16x8*)(Ke1 + (kb * 16 + fr) * 136 + kf * 32 + fq * 8);
                    }
                    f32x4 t0 = {}, t1 = {};
#pragma unroll
                    for (int kf = 0; kf < 4; ++kf) {
                        t0 = __builtin_amdgcn_mfma_f32_16x16x32_bf16(a0f[kf], qf[kf], t0, 0, 0, 0);
                        t1 = __builtin_amdgcn_mfma_f32_16x16x32_bf16(a1f[kf], qf[kf], t1, 0, 0, 0);
                    }
#pragma unroll
                    for (int r = 0; r < 4; ++r) acc[kb][r] = qmI ? t1[r] : t0[r];
                }
                __builtin_amdgcn_s_setprio(0);
            }

#pragma unroll
            for (int kb = 0; kb < 4; ++kb) {
                f32x4 pj = *(const f32x4*)(&posL[0][kb * 16 + fq * 4]);
#pragma unroll
                for (int r = 0; r < 4; ++r) {
                    float di = qposf - pj[r];
                    acc[kb][r] -= sft * di * di;
                }
            }

            float lmax = acc[0][0];
#pragma unroll
            for (int kb = 0; kb < 4; ++kb)
#pragma unroll
                for (int r = 0; r < 4; ++r) lmax = fmaxf(lmax, acc[kb][r]);
            if (!__all(lmax <= mrun + 8.f)) {
                float mn = fmaxf(mrun, lmax);
                mn = fmaxf(mn, __shfl_xor(mn, 16));
                mn = fmaxf(mn, __shfl_xor(mn, 32));
                float sc = __expf(mrun - mn);
                mrun = mn;
                lrun *= sc;
#pragma unroll
                for (int fd = 0; fd < 4; ++fd)
#pragma unroll
                    for (int r = 0; r < 4; ++r) ot[fd][r] *= sc;
            }
            float sum = 0.f;
#pragma unroll
            for (int kb = 0; kb < 4; ++kb)
#pragma unroll
                for (int r = 0; r < 4; ++r) {
                    int ko = kb * 16 + fq * 4 + r;
                    float p = ((int)(kbits >> ko) & 1) ? __expf(acc[kb][r] - mrun) : 0.f;
                    acc[kb][r] = p;
                    sum += p;
                }
            sum += __shfl_xor(sum, 16);
            sum += __shfl_xor(sum, 32);
            lrun += sum;

            __builtin_amdgcn_s_setprio(1);
#pragma unroll
            for (int half = 0; half < 2; ++half) {
#pragma unroll
                for (int kk = 0; kk < 2; ++kk) {
                    int kb = half * 2 + kk;
                    bf16x4 pk;
#pragma unroll
                    for (int r = 0; r < 4; ++r) pk[r] = (__bf16)acc[kb][r];
                    *(bf16x4*)(Sw + fr * 40 + kk * 16 + fq * 4) = pk;
                }
                bf16x8 pf = *(const bf16x8*)(Sw + fr * 40 + fq * 8);
#pragma unroll
                for (int fd = 0; fd < 4; ++fd) {
                    bf16x8 vf = *(const bf16x8*)(Vts[0] + (fd * 16 + fr) * 72 + half * 32 + fq * 8);
                    ot[fd] = __builtin_amdgcn_mfma_f32_16x16x32_bf16(vf, pf, ot[fd], 0, 0, 0);
                }
            }
            __builtin_amdgcn_s_setprio(0);
        }
#undef LOADM
    }

    // ---- epilogue: O -> dead Ke0 (flat [128][72]) -> coalesced scatter via perm ----
    __syncthreads();
    {
        const float inv = 1.0f / lrun;
        __bf16* Ew = Ke0 + (size_t)(wid * 16) * 72;
#pragma unroll
        for (int fd = 0; fd < 4; ++fd) {
            bf16x4 o;
#pragma unroll
            for (int r = 0; r < 4; ++r) o[r] = (__bf16)(ot[fd][r] * inv);
            *(bf16x4*)(Ew + fr * 72 + fd * 16 + fq * 4) = o;
        }
    }
    __syncthreads();
    {
        int r = tid >> 2, c = tid & 3;
        int pir = perm[b * LL + q0blk + r];
        const __bf16* src = Ke0 + (size_t)r * 72;
        __bf16* dst = AO + ((size_t)(b * LL + pir)) * DM + h * 64;
        *(bf16x8*)(dst + c * 8)      = *(const bf16x8*)(src + c * 8);
        *(bf16x8*)(dst + 32 + c * 8) = *(const bf16x8*)(src + 32 + c * 8);
    }
}

extern "C" void kernel_launch(void* const* d_in, const int* in_sizes, int n_in,
                              void* d_out, int out_size, void* d_ws, size_t ws_size,
                              hipStream_t stream) {
    const float* x     = (const float*)d_in[0];
    const int*   mask  = (const int*)d_in[1];
    const int*   qmask = (const int*)d_in[2];
    const float* W_qkv = (const float*)d_in[3];
    const float* W_pos = (const float*)d_in[4];
    const float* W_fc  = (const float*)d_in[5];
    const float* b_fc  = (const float*)d_in[6];
    const float* shift = (const float*)d_in[7];
    const float* bias  = (const float*)d_in[8];
    float* out = (float*)d_out;

    __bf16* Qcb  = (__bf16*)d_ws;           // [8,16,512,128]
    __bf16* K1cb = Qcb  + 8388608;
    __bf16* K2cb = K1cb + 8388608;
    __bf16* Vnb  = K2cb + 8388608;          // [8,16,512,64]
    __bf16* Vtb  = Vnb  + 4194304;          // [8,16,64,512] (key-permuted)
    __bf16* Xb   = Vtb  + 4194304;          // [4096,1024]
    __bf16* Wqkvb = Xb  + 4194304;          // [4096,1024] remapped
    __bf16* AOb   = Xb;                     // alias (attn writes after gemm reads)
    __bf16* PEb   = Wqkvb + 4194304;        // [512,64] bf16
    __bf16* Wposb = PEb + 32768;            // [3072,64] bf16
    __bf16* Wfcb  = Wposb + 196608;         // [1024,1024] bf16
    int* permA = (int*)(Wfcb + 1048576);    // [8,512]
    int* nzA   = permA + 4096;              // [8]
    int* pmaskA = nzA + 8;                  // [8,512]
    float* posfA = (float*)(pmaskA + 4096); // [8,512]
    int* schedA = (int*)(posfA + 4096);     // [512]

    prep_kernel<<<2424, 512, 0, stream>>>(qmask, mask, x, W_qkv, W_pos, W_fc,
                                          permA, pmaskA, posfA, nzA, schedA,
                                          PEb, Wposb, Wfcb, Xb, Wqkvb);
    gemm_fused<<<1120, 256, 0, stream>>>(Xb, Wqkvb, PEb, Wposb,
                                         Qcb, K1cb, K2cb, Vnb);
    vtrans_kernel<<<1024, 256, 0, stream>>>(Vnb, permA, Vtb);
    attn_kernel<<<512, 512, 0, stream>>>(Qcb, K1cb, K2cb, Vtb, pmaskA, permA,
                                         posfA, nzA, schedA, shift, AOb);
    gemm_out<<<dim3(8, 32), 256, 0, stream>>>(AOb, Wfcb, out, b_fc);
}